// Round 5
// baseline (872.664 us; speedup 1.0000x reference)
//
#include <hip/hip_runtime.h>
#include <math.h>

// Problem constants
#define B_ 8
#define N_ 5000
#define E_ 160000
#define M_ 40000      // N_*B_ rows, r = n*B_ + b
#define K_ 512
#define XT_ 157       // ceil(M_/256) row tiles

typedef __bf16 v8bf __attribute__((ext_vector_type(8)));
typedef float  v4f  __attribute__((ext_vector_type(4)));
typedef unsigned short u16x4v __attribute__((ext_vector_type(4)));
typedef unsigned short u16x8v __attribute__((ext_vector_type(8)));

__device__ __forceinline__ unsigned short f2b(float f){
  unsigned int u = __builtin_bit_cast(unsigned int, f);
  u += 0x7FFFu + ((u >> 16) & 1u);          // round-to-nearest-even
  return (unsigned short)(u >> 16);
}
__device__ __forceinline__ float b2f(unsigned short s){
  return __builtin_bit_cast(float, ((unsigned int)s) << 16);
}
__device__ __forceinline__ float softplus_(float x){
  // HW v_exp/v_log; x>15 -> x (exp overflow guard); bf16 output absorbs ~1e-6 err
  return (x > 15.0f) ? x : __logf(1.0f + __expf(x));
}
__device__ __forceinline__ float tanh_(float x){
  float e = __expf(2.0f*x);
  return 1.0f - 2.0f/(e + 1.0f);
}

// ---------------- setup kernels ----------------

__global__ __launch_bounds__(256) void zero_int2(int* a, int* b, int n){
  int i = blockIdx.x*256 + threadIdx.x;
  if (i < n){ a[i] = 0; b[i] = 0; }
}

// 5 * 131072 weight elems + 1024 packed bias. m: 0->WA, 1..4->Wall rows [Fc;Gc;Z;Fh]
__global__ __launch_bounds__(256) void convert_weights(
    const float* __restrict__ wA, const float* __restrict__ wFc,
    const float* __restrict__ wGc, const float* __restrict__ wZ,
    const float* __restrict__ wFh,
    const float* __restrict__ bFc, const float* __restrict__ bGc,
    const float* __restrict__ bZ,  const float* __restrict__ bFh,
    unsigned short* __restrict__ WA, unsigned short* __restrict__ Wall,
    float* __restrict__ biasP)
{
  int idx = blockIdx.x*256 + threadIdx.x;      // < 656384
  if (idx >= 655360){
    int j = idx - 655360;                      // 0..1023
    int mat = j >> 8, jj = j & 255;
    const float* bp = (mat == 0) ? bFc : (mat == 1) ? bGc : (mat == 2) ? bZ : bFh;
    biasP[j] = bp[jj];
    return;
  }
  int m = idx >> 17;                           // 131072 = 2^17
  int i = idx & 131071;
  float v;
  if      (m == 0) v = wA[i];
  else if (m == 1) v = wFc[i];
  else if (m == 2) v = wGc[i];
  else if (m == 3) v = wZ[i];
  else             v = wFh[i];
  unsigned short o = f2b(v);
  if (m == 0) WA[i] = o;
  else        Wall[(m-1)*131072 + i] = o;
}

// u (B,N,512) fp32 -> cB[r*256+q] bf16 (c part), hT[r*256+q] bf16 (h part), r=n*B+b
__global__ __launch_bounds__(256) void convert_u(
    const float* __restrict__ u, unsigned short* __restrict__ cB,
    unsigned short* __restrict__ hT)
{
  int r = blockIdx.x*4 + (threadIdx.x >> 6);
  int l = threadIdx.x & 63;
  int n = r >> 3, b = r & 7;
  const float* up = u + (size_t)(b*N_ + n)*512 + l*4;
  float4 cf = *(const float4*)up;
  float4 hf = *(const float4*)(up + 256);
  u16x4v c4, h4;
  c4.x = f2b(cf.x); c4.y = f2b(cf.y); c4.z = f2b(cf.z); c4.w = f2b(cf.w);
  h4.x = f2b(hf.x); h4.y = f2b(hf.y); h4.z = f2b(hf.z); h4.w = f2b(hf.w);
  *(u16x4v*)(cB + (size_t)r*256 + l*4) = c4;
  *(u16x4v*)(hT + (size_t)r*256 + l*4) = h4;
}

// ---------------- CSR build ----------------

__global__ __launch_bounds__(256) void hist_kernel(const int* __restrict__ dst, int* __restrict__ deg){
  int e = blockIdx.x*256 + threadIdx.x;   // exactly E_
  atomicAdd(&deg[dst[e]], 1);
}

__global__ __launch_bounds__(256) void scan_kernel(
    const int* __restrict__ deg, int* __restrict__ row_start, float* __restrict__ inv_deg)
{
  __shared__ int sums[256];
  int t = threadIdx.x;
  int base = t*20;
  int cnt[20];
  int local = 0;
#pragma unroll
  for (int i = 0; i < 20; ++i){
    int n = base + i;
    int d = (n < N_) ? deg[n] : 0;
    cnt[i] = d; local += d;
  }
  sums[t] = local; __syncthreads();
  for (int s = 1; s < 256; s <<= 1){
    int v = (t >= s) ? sums[t - s] : 0;
    __syncthreads();
    sums[t] += v;
    __syncthreads();
  }
  int prefix = (t == 0) ? 0 : sums[t-1];
#pragma unroll
  for (int i = 0; i < 20; ++i){
    int n = base + i;
    if (n < N_){
      row_start[n] = prefix;
      int d = cnt[i];
      inv_deg[n] = 1.0f / (float)((d > 1) ? d : 1);
      prefix += d;
    }
  }
  if (t == 255) row_start[N_] = prefix;
}

__global__ __launch_bounds__(256) void fill_kernel(
    const int* __restrict__ src, const int* __restrict__ dst,
    const int* __restrict__ row_start, int* __restrict__ cursor, int* __restrict__ csr)
{
  int e = blockIdx.x*256 + threadIdx.x;
  int d = dst[e];
  int p = atomicAdd(&cursor[d], 1);
  csr[row_start[d] + p] = src[e];
}

// one BLOCK per node n: 256 threads cover 8 batches x 32 col-segments.
// Per edge the whole block reads one contiguous 4 KB run of hT (rows s*8..s*8+7),
// csr[e] is a uniform scalar load. 2-edge unroll for memory-level parallelism.
__global__ __launch_bounds__(256) void gather_n_kernel(
    const unsigned short* __restrict__ hT, const int* __restrict__ csr,
    const int* __restrict__ row_start, const float* __restrict__ inv_deg,
    unsigned short* __restrict__ aggT)
{
  const int n = blockIdx.x;
  const int tid = threadIdx.x;
  const int boff = (tid >> 5)*256 + (tid & 31)*8;   // b*256 + cs*8 (shorts)
  const int e0 = row_start[n], e1 = row_start[n+1];

  float acc[8] = {};
  int e = e0;
  for (; e + 1 < e1; e += 2){
    int s0 = csr[e], s1 = csr[e+1];
    u16x8v v0 = *(const u16x8v*)(hT + (size_t)s0*2048 + boff);
    u16x8v v1 = *(const u16x8v*)(hT + (size_t)s1*2048 + boff);
#pragma unroll
    for (int i = 0; i < 8; ++i) acc[i] += b2f(v0[i]) + b2f(v1[i]);
  }
  if (e < e1){
    int s0 = csr[e];
    u16x8v v0 = *(const u16x8v*)(hT + (size_t)s0*2048 + boff);
#pragma unroll
    for (int i = 0; i < 8; ++i) acc[i] += b2f(v0[i]);
  }
  const float inv = inv_deg[n];
  u16x8v o;
#pragma unroll
  for (int i = 0; i < 8; ++i) o[i] = f2b(acc[i]*inv);
  *(u16x8v*)(aggT + (size_t)n*2048 + boff) = o;
}

// ---------------- tiled GEMM: 256x128 tile, 512 threads / 8 waves ----------------
// C[m, n] = act( [A0|A1](m, 0:512) . Bw(n, 0:512) + bias[n] )
// 8 waves = 4 row-groups x 2 col-groups of 64x64; BK=64; global_load_lds staging
// with XOR-chunk swizzle on the GLOBAL address (LDS slots lane-contiguous as
// global_load_lds requires; fragment ds_read_b128 conflict-free).
// 2x MFMA per barrier vs the 128x128 tile -> half the vmcnt-drain events.
// 1-D grid, id decode groups all NY col-slab blocks of 8 row-tiles into a
// window with id % 8 == const -> same XCD under round-robin dispatch -> the A
// row-tile is fetched from HBM once, L2 serves the other NY-1 re-reads.
// Epilogue: two 128-row phases repack through LDS -> 16B/lane coalesced stores.
// MODE 0 (NY=2): gemm1 -> dst[r*256 + col], softplus.
// MODE 1 (NY=8): gemm_big -> act[(b*N+n)*1024 + col], tanh on slab y>>1==2.

template<int MODE>
__global__ __launch_bounds__(512, 6) void gemm_tiled(
    const unsigned short* __restrict__ A0, const unsigned short* __restrict__ A1,
    const unsigned short* __restrict__ Bw, const float* __restrict__ bias,
    unsigned short* dstp)
{
  const int id = blockIdx.x;
  int x, y;
  if (MODE == 1){
    const int u6 = id & 63;
    y = u6 >> 3;
    x = (id >> 6)*8 + (u6 & 7);
  } else {
    const int u4 = id & 15;
    y = u4 >> 3;
    x = (id >> 4)*8 + (u4 & 7);
  }
  if (x >= XT_) return;

  __shared__ unsigned short lds[24576];       // A 256x64 (32KB) + B 128x64 (16KB); epilogue reuse 128x136
  unsigned short* lA = lds;                   // 16384 shorts
  unsigned short* lB = lds + 16384;           // 8192 shorts

  const int tid = threadIdx.x;
  const int w  = tid >> 6, l = tid & 63;
  const int wr = w >> 1,  wc = w & 1;         // wr 0..3 (64-row group), wc 0..1 (64-col group)
  const int lq = l >> 4,  lr = l & 15;
  const int m0 = x * 256;
  const int n0 = y * 128;

  v4f acc[4][4] = {};
#pragma unroll 1
  for (int kb = 0; kb < 8; ++kb){
    const unsigned short* As = (kb < 4) ? A0 : A1;
    const int ak = (kb & 3) * 64;
    __syncthreads();
    // A: 2048 16B-chunks (row = c>>3, lds slot = c&7, global chunk = (c&7)^(row&7))
#pragma unroll
    for (int i = 0; i < 4; ++i){
      const int ci  = i*512 + tid;
      const int row = ci >> 3;
      const int sl  = (ci & 7) ^ (row & 7);
      const unsigned short* gpA = As + (size_t)(m0 + row)*256 + ak + sl*8;
      __builtin_amdgcn_global_load_lds((const __attribute__((address_space(1))) void*)gpA,
                                       (__attribute__((address_space(3))) void*)(lA + ci*8), 16, 0, 0);
    }
    // B: 1024 chunks
#pragma unroll
    for (int i = 0; i < 2; ++i){
      const int cb  = i*512 + tid;
      const int row = cb >> 3;
      const int sl  = (cb & 7) ^ (row & 7);
      const unsigned short* gpB = Bw + (size_t)(n0 + row)*512 + kb*64 + sl*8;
      __builtin_amdgcn_global_load_lds((const __attribute__((address_space(1))) void*)gpB,
                                       (__attribute__((address_space(3))) void*)(lB + cb*8), 16, 0, 0);
    }
    __syncthreads();
#pragma unroll
    for (int ks = 0; ks < 2; ++ks){
      v8bf a[4], b[4];
#pragma unroll
      for (int rt = 0; rt < 4; ++rt){
        const int ar = wr*64 + rt*16 + lr;
        a[rt] = *(const v8bf*)(lA + ar*64 + (((ks*4 + lq) ^ (ar & 7)))*8);
      }
#pragma unroll
      for (int ct = 0; ct < 4; ++ct){
        const int br = wc*64 + ct*16 + lr;
        b[ct] = *(const v8bf*)(lB + br*64 + (((ks*4 + lq) ^ (br & 7)))*8);
      }
#pragma unroll
      for (int rt = 0; rt < 4; ++rt)
#pragma unroll
        for (int ct = 0; ct < 4; ++ct)
          acc[rt][ct] = __builtin_amdgcn_mfma_f32_16x16x32_bf16(a[rt], b[ct], acc[rt][ct], 0, 0, 0);
    }
  }

  float bv[4];
#pragma unroll
  for (int ct = 0; ct < 4; ++ct) bv[ct] = bias[n0 + wc*64 + ct*16 + lr];

  const bool is_tanh = (MODE == 1) && ((y >> 1) == 2);

  // two-phase epilogue: 128 rows per phase repacked via LDS, coalesced stores
#pragma unroll 1
  for (int p = 0; p < 2; ++p){
    __syncthreads();           // phase 0: done reading lA/lB; phase 1: stores done
    if ((wr >> 1) == p){
#pragma unroll
      for (int rt = 0; rt < 4; ++rt){
#pragma unroll
        for (int ct = 0; ct < 4; ++ct){
          const int col = wc*64 + ct*16 + lr;
#pragma unroll
          for (int reg = 0; reg < 4; ++reg){
            const int row = (wr & 1)*64 + rt*16 + lq*4 + reg;
            const float xv = acc[rt][ct][reg] + bv[ct];
            lds[row*136 + col] = f2b(is_tanh ? tanh_(xv) : softplus_(xv));
          }
        }
      }
    }
    __syncthreads();
#pragma unroll
    for (int i = 0; i < 4; ++i){
      const int row = i*32 + (tid >> 4);
      const int r = m0 + p*128 + row;
      if (r < M_){
        const uint4 v = *(const uint4*)(lds + row*136 + (tid & 15)*8);
        if (MODE == 0){
          *(uint4*)(dstp + (size_t)r*256 + n0 + (tid & 15)*8) = v;
        } else {
          const int n = r >> 3, b = r & 7;
          *(uint4*)(dstp + ((size_t)b*N_ + n)*1024 + n0 + (tid & 15)*8) = v;
        }
      }
    }
  }
}

// ---------------- epilogue: dc with projection + dh ----------------
// One wave per row r. act aliases out (same row region) — reads complete before
// stores within the wave; no __restrict__ so the compiler keeps the order.

__global__ __launch_bounds__(256) void epilogue_kernel(
    const unsigned short* act, const float* __restrict__ u, float* out)
{
  int r = blockIdx.x*4 + (threadIdx.x >> 6);
  int l = threadIdx.x & 63;
  int n = r >> 3, b = r & 7;
  const size_t rr = (size_t)(b*N_ + n);
  const unsigned short* arow = act + rr*1024;
  const float* urow = u + rr*512;
  float* orow = out + rr*512;

  u16x4v fc4 = *(const u16x4v*)(arow +        l*4);
  u16x4v gc4 = *(const u16x4v*)(arow + 256 +  l*4);
  u16x4v z4  = *(const u16x4v*)(arow + 512 +  l*4);
  u16x4v fh4 = *(const u16x4v*)(arow + 768 +  l*4);
  float4 c4f = *(const float4*)(urow + l*4);
  float4 h4f = *(const float4*)(urow + 256 + l*4);

  float c[4] = {c4f.x, c4f.y, c4f.z, c4f.w};
  float h[4] = {h4f.x, h4f.y, h4f.z, h4f.w};
  float dc[4], fh[4];
  float num = 0.f, den = 0.f;
#pragma unroll
  for (int i = 0; i < 4; ++i){
    float fc = b2f(fc4[i]), gc = b2f(gc4[i]), z = b2f(z4[i]);
    fh[i] = b2f(fh4[i]);
    dc[i] = -fc*c[i] + gc*z;
    num += dc[i]*c[i];
    den += c[i]*c[i];
  }
#pragma unroll
  for (int s = 1; s < 64; s <<= 1){
    num += __shfl_xor(num, s, 64);
    den += __shfl_xor(den, s, 64);
  }
  const float proj = num / den;

  float4 o, oh;
  o.x = dc[0] - proj*c[0]; o.y = dc[1] - proj*c[1];
  o.z = dc[2] - proj*c[2]; o.w = dc[3] - proj*c[3];
  oh.x = -fh[0]*h[0]; oh.y = -fh[1]*h[1];
  oh.z = -fh[2]*h[2]; oh.w = -fh[3]*h[3];
  *(float4*)(orow + l*4) = o;
  *(float4*)(orow + 256 + l*4) = oh;
}

// ---------------- launch ----------------

extern "C" void kernel_launch(void* const* d_in, const int* in_sizes, int n_in,
                              void* d_out, int out_size, void* d_ws, size_t ws_size,
                              hipStream_t stream) {
  const float* u    = (const float*)d_in[0];
  const int*   src  = (const int*)d_in[1];
  const int*   dst  = (const int*)d_in[2];
  const float* wFc  = (const float*)d_in[4];
  const float* bFc  = (const float*)d_in[5];
  const float* wFh  = (const float*)d_in[6];
  const float* bFh  = (const float*)d_in[7];
  const float* wGc  = (const float*)d_in[8];
  const float* bGc  = (const float*)d_in[9];
  const float* wZ   = (const float*)d_in[10];
  const float* bZ   = (const float*)d_in[11];
  const float* wA   = (const float*)d_in[12];
  const float* bA   = (const float*)d_in[13];
  float* out = (float*)d_out;
  unsigned short* act = (unsigned short*)d_out;   // bf16 activations overlay out

  // ws layout. GEMM staging over-reads up to 192 rows (~96 KB) past the end of
  // hT/cB/aggT/hB — each overflow lands in the NEXT allocation (readable garbage,
  // results discarded by the r < M_ store guard). Keep this buffer order.
  char* W = (char*)d_ws;
  unsigned short* hT   = (unsigned short*)(W + 0);           // 20,480,000 B
  unsigned short* cB   = (unsigned short*)(W + 20480000);
  unsigned short* aggT = (unsigned short*)(W + 40960000);
  unsigned short* hB   = (unsigned short*)(W + 61440000);
  unsigned short* WA   = (unsigned short*)(W + 81920000);    // 262,144 B
  unsigned short* Wall = (unsigned short*)(W + 82182144);    // 1,048,576 B
  float* biasP   = (float*)(W + 83230720);                   // 4,096 B
  int* deg       = (int*)(W + 83234816);
  int* row_start = (int*)(W + 83255296);
  int* cursor    = (int*)(W + 83275776);
  int* csr       = (int*)(W + 83296256);                     // 640,000 B
  float* inv_deg = (float*)(W + 83936256);

  zero_int2<<<(N_ + 255)/256, 256, 0, stream>>>(deg, cursor, N_);
  convert_weights<<<2564, 256, 0, stream>>>(wA, wFc, wGc, wZ, wFh,
                                            bFc, bGc, bZ, bFh, WA, Wall, biasP);
  convert_u<<<M_/4, 256, 0, stream>>>(u, cB, hT);
  hist_kernel<<<E_/256, 256, 0, stream>>>(dst, deg);
  scan_kernel<<<1, 256, 0, stream>>>(deg, row_start, inv_deg);
  fill_kernel<<<E_/256, 256, 0, stream>>>(src, dst, row_start, cursor, csr);
  gather_n_kernel<<<N_, 256, 0, stream>>>(hT, csr, row_start, inv_deg, aggT);

  // 1-D swizzled grids: 20 g-groups of 8 x-tiles (x<157 guard inside)
  gemm_tiled<0><<<20*16, 512, 0, stream>>>(hT, aggT, WA, bA, hB);
  gemm_tiled<1><<<20*64, 512, 0, stream>>>(cB, hB, Wall, biasP, act);

  epilogue_kernel<<<M_/4, 256, 0, stream>>>(act, u, out);
}